// Round 19
// baseline (181.778 us; speedup 1.0000x reference)
//
#include <hip/hip_runtime.h>
#include <hip/hip_bf16.h>

// B=4, C=256, C8=32 (=Dn), H=W=64, N=4096. fp32 I/O; bf16 internal.
#define Bn 4
#define Cn 256
#define Dn 32
#define Nn 4096

typedef __bf16 bf16x8 __attribute__((ext_vector_type(8)));
typedef float f32x4 __attribute__((ext_vector_type(4)));

__device__ __forceinline__ float bf2f(unsigned short u) {
  unsigned int v = ((unsigned int)u) << 16;
  return __builtin_bit_cast(float, v);
}
__device__ __forceinline__ unsigned short f2bf(float f) {
  unsigned int v = __builtin_bit_cast(unsigned int, f);
  v += 0x7FFFu + ((v >> 16) & 1u);  // RNE
  return (unsigned short)(v >> 16);
}
// hardware packed cvt: 2 fp32 -> 2 bf16 (v_cvt_pk_bf16_f32)
__device__ __forceinline__ unsigned int pk2(float a, float b) {
  union { __hip_bfloat162 h; unsigned int u; } x;
  x.h = __float22bfloat162_rn(make_float2(a, b));
  return x.u;
}
__device__ __forceinline__ bf16x8 ldfrag(const unsigned short* p) {
  return __builtin_bit_cast(bf16x8, *(const uint4*)p);
}
__device__ __forceinline__ uint4 pack8(const float* p) {
  float4 a = *(const float4*)p;
  float4 b = *(const float4*)(p + 4);
  union { unsigned int u2[4]; uint4 u; } x;
  x.u2[0] = pk2(a.x, a.y); x.u2[1] = pk2(a.z, a.w);
  x.u2[2] = pk2(b.x, b.y); x.u2[3] = pk2(b.z, b.w);
  return x.u;
}
// async global->LDS, 16 B per lane (lds dest = wave-uniform base + lane*16)
__device__ __forceinline__ void async16(unsigned short* lds, const unsigned short* g) {
  __builtin_amdgcn_global_load_lds(
      (const __attribute__((address_space(1))) unsigned int*)g,
      (__attribute__((address_space(3))) unsigned int*)lds, 16, 0, 0);
}

// ---------------------------------------------------------------------------
// Kernel 0: wconv — convert Wq/Wk/Wv fp32 -> bf16 ONCE.
// ---------------------------------------------------------------------------
__global__ __launch_bounds__(256) void wconv(
    const float* __restrict__ Wq, const float* __restrict__ Wk,
    const float* __restrict__ Wv,
    unsigned short* __restrict__ WqBf, unsigned short* __restrict__ WkBf,
    unsigned short* __restrict__ WvBf)
{
  const size_t base = ((size_t)blockIdx.x * 256 + threadIdx.x) * 8;
  if (base < 8192) {
    *(uint4*)(WqBf + base) = pack8(Wq + base);
  } else if (base < 16384) {
    *(uint4*)(WkBf + base - 8192) = pack8(Wk + base - 8192);
  } else {
    *(uint4*)(WvBf + base - 16384) = pack8(Wv + base - 16384);
  }
}

// ---------------------------------------------------------------------------
// Kernel 1: qkprep v9 (unchanged from R17, best 181.4 total): v4 geometry +
// LDS-staged transpose of pre/post; coalesced float4 staging, b128 LDS
// B-fragments, epilogues byte-identical to v4. LDS 35840 B.
// Qt scaled by log2(e) so flash softmax uses raw exp2.
// ---------------------------------------------------------------------------
#define PSTR 280  // padded row stride (elements); 560 B rows
__global__ __launch_bounds__(256) void qkprep(
    const float* __restrict__ pre, const float* __restrict__ post,
    const unsigned short* __restrict__ WqBf, const float* __restrict__ bq,
    const unsigned short* __restrict__ WkBf, const float* __restrict__ bk,
    const unsigned short* __restrict__ WvBf, const float* __restrict__ bv,
    unsigned short* __restrict__ Qt, unsigned short* __restrict__ Kt,
    unsigned short* __restrict__ VBf)
{
  __shared__ __align__(16) unsigned short smem[2 * 32 * PSTR];  // 35840 B
  unsigned short* sPre  = smem;               // [32 i][PSTR]
  unsigned short* sPost = smem + 32 * PSTR;   // [32 i][PSTR]
  unsigned short* sV    = smem;               // aliased after barrier (20 KB)

  const int tid = threadIdx.x;
  const int lane = tid & 63, w = tid >> 6;
  const int quad = lane >> 4, n16 = lane & 15;
  const int b = blockIdx.x >> 7;
  const int i0 = (blockIdx.x & 127) << 5;
  const int isub = w & 1, dh = w >> 1;
  const int i = i0 + isub * 16 + n16;

  // ---- stage: pre/post [256 c][32 i] fp32 -> LDS bf16 [i][c] transposed ----
#pragma unroll
  for (int it = 0; it < 8; it++) {
    const int idx = it * 256 + tid;
    const int c = idx >> 3, ioff = (idx & 7) << 2;
    const size_t goff = ((size_t)b * Cn + c) * Nn + i0 + ioff;
    float4 vp = *(const float4*)(pre + goff);
    float4 vq = *(const float4*)(post + goff);
    sPre[(ioff + 0) * PSTR + c] = f2bf(vp.x);
    sPre[(ioff + 1) * PSTR + c] = f2bf(vp.y);
    sPre[(ioff + 2) * PSTR + c] = f2bf(vp.z);
    sPre[(ioff + 3) * PSTR + c] = f2bf(vp.w);
    sPost[(ioff + 0) * PSTR + c] = f2bf(vq.x);
    sPost[(ioff + 1) * PSTR + c] = f2bf(vq.y);
    sPost[(ioff + 2) * PSTR + c] = f2bf(vq.z);
    sPost[(ioff + 3) * PSTR + c] = f2bf(vq.w);
  }
  __syncthreads();

  const f32x4 zz = {0.f, 0.f, 0.f, 0.f};
  f32x4 aq = zz, ak = zz;
  f32x4 accv[8];
#pragma unroll
  for (int ct = 0; ct < 8; ct++) accv[ct] = zz;

  const int irow = (isub * 16 + n16) * PSTR;

#pragma unroll
  for (int kc = 0; kc < 8; kc++) {
    const int co = kc * 32 + quad * 8;
    bf16x8 bp  = ldfrag(sPost + irow + co);   // post[co..co+7][i]
    bf16x8 bq8 = ldfrag(sPre + irow + co);    // pre[co..co+7][i]
    bf16x8 awq = ldfrag(WqBf + (size_t)(dh * 16 + n16) * Cn + co);
    bf16x8 awk = ldfrag(WkBf + (size_t)(dh * 16 + n16) * Cn + co);
    aq = __builtin_amdgcn_mfma_f32_16x16x32_bf16(awq, bp, aq, 0, 0, 0);
    ak = __builtin_amdgcn_mfma_f32_16x16x32_bf16(awk, bq8, ak, 0, 0, 0);
#pragma unroll
    for (int ct = 0; ct < 8; ct++) {
      bf16x8 aw = ldfrag(WvBf + (size_t)(dh * 128 + ct * 16 + n16) * Cn + co);
      accv[ct] = __builtin_amdgcn_mfma_f32_16x16x32_bf16(aw, bq8, accv[ct], 0, 0, 0);
    }
  }

  // Q/K epilogue (identical to v4)
  const float LOG2E = 1.44269504f;
  union { unsigned short s[4]; uint2 u; } oq, ok;
#pragma unroll
  for (int r = 0; r < 4; r++) {
    int d = dh * 16 + quad * 4 + r;
    oq.s[r] = f2bf((aq[r] + bq[d]) * LOG2E);
    ok.s[r] = f2bf(ak[r] + bk[d]);
  }
  *(uint2*)(Qt + ((size_t)b * Nn + i) * Dn + dh * 16 + quad * 4) = oq.u;
  *(uint2*)(Kt + ((size_t)b * Nn + i) * Dn + dh * 16 + quad * 4) = ok.u;

  // V epilogue: reuse smem as sV after all fragment reads done
  __syncthreads();
#pragma unroll
  for (int ct = 0; ct < 8; ct++) {
#pragma unroll
    for (int r = 0; r < 4; r++) {
      const int c = dh * 128 + ct * 16 + quad * 4 + r;
      sV[c * 40 + isub * 16 + n16] = f2bf(accv[ct][r] + bv[c]);
    }
  }
  __syncthreads();
#pragma unroll
  for (int k = 0; k < 4; k++) {
    const int slot = tid + k * 256;          // 1024 = 256 c x 4 n-octets
    const int c = slot >> 2, seg = slot & 3;
    *(uint4*)(VBf + ((size_t)b * Cn + c) * Nn + i0 + seg * 8) =
        *(const uint4*)(sV + c * 40 + seg * 8);
  }
}

// ---------------------------------------------------------------------------
// Kernel 2: flash attention v14 = v13 minus s_setprio. T5 evidence (m190):
// setprio is null-to-NEGATIVE on barrier-locked lockstep structures — v13's
// 4 waves are exactly that (no role-split to arbitrate). XCD-aware
// bijective swizzle retained (FETCH 37.4 -> 5.7 MB, the R10 win).
// ---------------------------------------------------------------------------
__global__ __launch_bounds__(256, 4) void flash_attn(
    const unsigned short* __restrict__ Qt, const unsigned short* __restrict__ Kt,
    const unsigned short* __restrict__ VBf,
    unsigned short* __restrict__ Opart, float* __restrict__ Lpart)
{
  __shared__ __align__(16) unsigned short sX[256 * 64];  // 32 KB
  __shared__ __align__(16) unsigned short Pl[64 * 64];   // 8 KB (swizzled)

  const int tid = threadIdx.x;
  const int lane = tid & 63, w = tid >> 6;
  const int quad = lane >> 4, n16 = lane & 15;
  // XCD-aware decode: pair (bid&7) -> xcd owns (b, js-half); bijective.
  const int bid = blockIdx.x;
  const int pair = bid & 7, sub = bid >> 3;      // sub in 0..127
  const int b  = pair >> 1;
  const int js = ((pair & 1) << 1) | (sub >> 6);
  const int it = sub & 63;
  const int i0 = it * 64;
  const int jbase = js * 1024;

  // Q B-frag for wave's own 16-i subtile (S^T: B n=i, k=d)
  const bf16x8 qf = ldfrag(Qt + ((size_t)b * Nn + i0 + w * 16 + n16) * Dn + quad * 8);

  const f32x4 zz = {0.f, 0.f, 0.f, 0.f};
  f32x4 acc[4][4];                       // [i-sub][c-tile within wave's 64 c]
#pragma unroll
  for (int sub2 = 0; sub2 < 4; sub2++)
#pragma unroll
    for (int ct = 0; ct < 4; ct++) acc[sub2][ct] = zz;
  float lrow = 0.f;                      // softmax denom, col i = n16 (dup x4)

  const size_t laneoff = (size_t)(lane >> 3) * Nn + (size_t)(((lane & 7) ^ (lane >> 3)) << 3);
  const unsigned short* preB = VBf + (size_t)b * Cn * Nn + laneoff;
  const int xsw = n16 & 7;
  const int xoff0 = (quad ^ xsw) << 3;
  const int xoff1 = ((4 + quad) ^ xsw) << 3;
  const int psw = (n16 & 7) << 3;        // Pl XOR swizzle (16B units per 8 rows)

  for (int t = 0; t < 16; ++t) {
    const int j0 = jbase + t * 64;
    __syncthreads();                     // sX(t-1)/Pl(t-1) fully consumed
    // async stage V tile 256c x 64j (XOR col swizzle), 8 x 16B per lane
#pragma unroll
    for (int k = 0; k < 8; k++) {
      const int rb = (k * 4 + w) * 8;
      async16(sX + rb * 64 + (lane << 3), preB + (size_t)rb * Nn + j0);
    }
    // S^T = K Q^T for wave's 16 i; K b128 direct from L2-resident Kt
    {
      f32x4 sc[4];
#pragma unroll
      for (int jt = 0; jt < 4; jt++) {
        bf16x8 akf = ldfrag(Kt + ((size_t)b * Nn + j0 + jt * 16 + n16) * Dn + quad * 8);
        sc[jt] = __builtin_amdgcn_mfma_f32_16x16x32_bf16(akf, qf, zz, 0, 0, 0);
      }
      float ps = 0.f;
#pragma unroll
      for (int jt = 0; jt < 4; jt++) {
        float p0 = exp2f(fminf(sc[jt][0], 101.f));
        float p1 = exp2f(fminf(sc[jt][1], 101.f));
        float p2 = exp2f(fminf(sc[jt][2], 101.f));
        float p3 = exp2f(fminf(sc[jt][3], 101.f));
        ps += (p0 + p1) + (p2 + p3);
        union { unsigned int u2[2]; uint2 u; } pk;
        pk.u2[0] = pk2(p0, p1);
        pk.u2[1] = pk2(p2, p3);
        // Pl[i][j], i = w*16+n16, j = jt*16+quad*4..+3 (XOR-swizzled cols)
        *(uint2*)&Pl[(size_t)(w * 16 + n16) * 64 + ((jt * 16 + quad * 4) ^ psw)] = pk.u;
      }
      ps += __shfl_xor(ps, 16);
      ps += __shfl_xor(ps, 32);
      lrow += ps;
    }
    __syncthreads();                     // DMA drained + Pl visible

    // PV(t): U[c][i] += V[c][j] P^T[j][i], 16x16x32 (k = 32 j)
#pragma unroll
    for (int kc = 0; kc < 2; kc++) {
      const int xo = kc ? xoff1 : xoff0;
      bf16x8 pB[4];
#pragma unroll
      for (int sub2 = 0; sub2 < 4; sub2++)
        pB[sub2] = ldfrag(&Pl[(size_t)(sub2 * 16 + n16) * 64 + ((kc * 32 + quad * 8) ^ psw)]);
#pragma unroll
      for (int ct = 0; ct < 4; ct++) {
        const int crow = w * 64 + ct * 16 + n16;
        bf16x8 av = ldfrag(&sX[crow * 64 + xo]);
        acc[0][ct] = __builtin_amdgcn_mfma_f32_16x16x32_bf16(av, pB[0], acc[0][ct], 0, 0, 0);
        acc[1][ct] = __builtin_amdgcn_mfma_f32_16x16x32_bf16(av, pB[1], acc[1][ct], 0, 0, 0);
        acc[2][ct] = __builtin_amdgcn_mfma_f32_16x16x32_bf16(av, pB[2], acc[2][ct], 0, 0, 0);
        acc[3][ct] = __builtin_amdgcn_mfma_f32_16x16x32_bf16(av, pB[3], acc[3][ct], 0, 0, 0);
      }
    }
  }

  // partial store: O bf16 [js*4+b][i][c], l fp32 [js*4+b][i]
  const size_t pbase = (size_t)(js * 4 + b) * Nn;
  if (quad == 0) Lpart[pbase + i0 + w * 16 + n16] = lrow;
#pragma unroll
  for (int sub2 = 0; sub2 < 4; sub2++) {
    const int i = i0 + sub2 * 16 + n16;
#pragma unroll
    for (int ct = 0; ct < 4; ct++) {
      union { unsigned int u2[2]; uint2 u; } pk;
      pk.u2[0] = pk2(acc[sub2][ct][0], acc[sub2][ct][1]);
      pk.u2[1] = pk2(acc[sub2][ct][2], acc[sub2][ct][3]);
      *(uint2*)(Opart + (pbase + i) * 256 + w * 64 + ct * 16 + quad * 4) = pk.u;
    }
  }
}

// ---------------------------------------------------------------------------
// Kernel 3: combine v2 — pure streaming merge (reverted to the R17 best-
// measured config; v3's XCD decode was a null).
// ---------------------------------------------------------------------------
__global__ __launch_bounds__(256) void combine(
    const unsigned short* __restrict__ Opart, const float* __restrict__ Lpart,
    const float* __restrict__ post, const float* __restrict__ gamma,
    float* __restrict__ out)
{
  __shared__ float sT[64 * 65];   // [c][i], stride 65
  __shared__ float sL[64];

  const int tid = threadIdx.x;
  const int b = blockIdx.x >> 8;
  const int rest = blockIdx.x & 255;
  const int i0 = (rest >> 2) * 64;
  const int c0 = (rest & 3) * 64;

  if (tid < 64) {
    float l = 0.f;
#pragma unroll
    for (int js = 0; js < 4; js++) l += Lpart[(size_t)(js * 4 + b) * Nn + i0 + tid];
    sL[tid] = 1.f / l;
  }
  __syncthreads();

  // accumulate 4 partials, normalize, write transposed into sT
#pragma unroll
  for (int pass = 0; pass < 2; pass++) {
    const int il = (tid >> 3) + pass * 32;   // 0..63
    const int c8 = (tid & 7) << 3;           // 0..56
    float a[8] = {0.f, 0.f, 0.f, 0.f, 0.f, 0.f, 0.f, 0.f};
#pragma unroll
    for (int js = 0; js < 4; js++) {
      uint4 uu = *(const uint4*)(Opart + ((size_t)(js * 4 + b) * Nn + i0 + il) * 256 + c0 + c8);
      const unsigned short* us = (const unsigned short*)&uu;
#pragma unroll
      for (int e = 0; e < 8; e++) a[e] += bf2f(us[e]);
    }
    const float inv = sL[il];
#pragma unroll
    for (int e = 0; e < 8; e++) sT[(c8 + e) * 65 + il] = a[e] * inv;
  }
  __syncthreads();

  const float g = gamma[0];
#pragma unroll
  for (int itr = 0; itr < 4; itr++) {
    const int slot = tid + itr * 256;        // 1024 = 64 c x 16 i-quads
    const int cr = slot >> 4, i4 = (slot & 15) << 2;
    const size_t addr = ((size_t)b * Cn + c0 + cr) * Nn + i0 + i4;
    float4 pp = *(const float4*)(post + addr);
    float4 ov;
    ov.x = g * sT[cr * 65 + i4 + 0] + pp.x;
    ov.y = g * sT[cr * 65 + i4 + 1] + pp.y;
    ov.z = g * sT[cr * 65 + i4 + 2] + pp.z;
    ov.w = g * sT[cr * 65 + i4 + 3] + pp.w;
    *(float4*)(out + addr) = ov;
  }
}

extern "C" void kernel_launch(void* const* d_in, const int* in_sizes, int n_in,
                              void* d_out, int out_size, void* d_ws, size_t ws_size,
                              hipStream_t stream) {
  const float* pre   = (const float*)d_in[0];
  const float* post  = (const float*)d_in[1];
  const float* Wq    = (const float*)d_in[2];
  const float* bq    = (const float*)d_in[3];
  const float* Wk    = (const float*)d_in[4];
  const float* bk    = (const float*)d_in[5];
  const float* Wv    = (const float*)d_in[6];
  const float* bv    = (const float*)d_in[7];
  const float* gamma = (const float*)d_in[8];
  float* out = (float*)d_out;

  unsigned short* ws = (unsigned short*)d_ws;
  unsigned short* Qt    = ws;                                   // 512K sh
  unsigned short* Kt    = Qt + (size_t)Bn * Nn * Dn;            // 512K sh
  unsigned short* VBf   = Kt + (size_t)Bn * Nn * Dn;            // 4M sh
  unsigned short* WqBf  = VBf + (size_t)Bn * Cn * Nn;           // 8K sh
  unsigned short* WkBf  = WqBf + Dn * Cn;                       // 8K sh
  unsigned short* WvBf  = WkBf + Dn * Cn;                       // 64K sh
  float* Lpart = (float*)(WvBf + Cn * Cn);                      // 64K fl
  unsigned short* Opart = (unsigned short*)(Lpart + 4 * Bn * Nn);  // 16.7M sh

  wconv<<<40, 256, 0, stream>>>(Wq, Wk, Wv, WqBf, WkBf, WvBf);
  qkprep<<<512, 256, 0, stream>>>(pre, post, WqBf, bq, WkBf, bk, WvBf, bv,
                                  Qt, Kt, VBf);
  flash_attn<<<1024, 256, 0, stream>>>(Qt, Kt, VBf, Opart, Lpart);
  combine<<<1024, 256, 0, stream>>>(Opart, Lpart, post, gamma, out);
}

// Round 20
// 179.525 us; speedup vs baseline: 1.0126x; 1.0126x over previous
//
#include <hip/hip_runtime.h>
#include <hip/hip_bf16.h>

// B=4, C=256, C8=32 (=Dn), H=W=64, N=4096. fp32 I/O; bf16 internal.
#define Bn 4
#define Cn 256
#define Dn 32
#define Nn 4096

typedef __bf16 bf16x8 __attribute__((ext_vector_type(8)));
typedef float f32x4 __attribute__((ext_vector_type(4)));

__device__ __forceinline__ float bf2f(unsigned short u) {
  unsigned int v = ((unsigned int)u) << 16;
  return __builtin_bit_cast(float, v);
}
__device__ __forceinline__ unsigned short f2bf(float f) {
  unsigned int v = __builtin_bit_cast(unsigned int, f);
  v += 0x7FFFu + ((v >> 16) & 1u);  // RNE
  return (unsigned short)(v >> 16);
}
// hardware packed cvt: 2 fp32 -> 2 bf16 (v_cvt_pk_bf16_f32)
__device__ __forceinline__ unsigned int pk2(float a, float b) {
  union { __hip_bfloat162 h; unsigned int u; } x;
  x.h = __float22bfloat162_rn(make_float2(a, b));
  return x.u;
}
__device__ __forceinline__ bf16x8 ldfrag(const unsigned short* p) {
  return __builtin_bit_cast(bf16x8, *(const uint4*)p);
}
__device__ __forceinline__ uint4 pack8(const float* p) {
  float4 a = *(const float4*)p;
  float4 b = *(const float4*)(p + 4);
  union { unsigned int u2[4]; uint4 u; } x;
  x.u2[0] = pk2(a.x, a.y); x.u2[1] = pk2(a.z, a.w);
  x.u2[2] = pk2(b.x, b.y); x.u2[3] = pk2(b.z, b.w);
  return x.u;
}
// async global->LDS, 16 B per lane (lds dest = wave-uniform base + lane*16)
__device__ __forceinline__ void async16(unsigned short* lds, const unsigned short* g) {
  __builtin_amdgcn_global_load_lds(
      (const __attribute__((address_space(1))) unsigned int*)g,
      (__attribute__((address_space(3))) unsigned int*)lds, 16, 0, 0);
}

// ---------------------------------------------------------------------------
// Kernel 0: wconv — convert Wq/Wk/Wv fp32 -> bf16 ONCE.
// ---------------------------------------------------------------------------
__global__ __launch_bounds__(256) void wconv(
    const float* __restrict__ Wq, const float* __restrict__ Wk,
    const float* __restrict__ Wv,
    unsigned short* __restrict__ WqBf, unsigned short* __restrict__ WkBf,
    unsigned short* __restrict__ WvBf)
{
  const size_t base = ((size_t)blockIdx.x * 256 + threadIdx.x) * 8;
  if (base < 8192) {
    *(uint4*)(WqBf + base) = pack8(Wq + base);
  } else if (base < 16384) {
    *(uint4*)(WkBf + base - 8192) = pack8(Wk + base - 8192);
  } else {
    *(uint4*)(WvBf + base - 16384) = pack8(Wv + base - 16384);
  }
}

// ---------------------------------------------------------------------------
// Kernel 1: qkprep v10 — role-split 512-thread blocks for 2x wave-level
// parallelism WITHOUT duplicating any global traffic. qkprep is L2-latency
// bound on ~88 weight-fragment loads/thread at 8 waves/CU (in-flight-load
// model: ~47 µs). v10: grid 512 (unchanged), 8 waves = isub(2) x role(4).
// Role r: V c-quarter [r*64,+64) (4 MFMA/kc) + (r<2 ? Q d-half r : K
// d-half r-2). Per-wave loads/kc 10 -> 5; waves/CU 8 -> 16; each weight
// element still loaded exactly once per block. Data path = v9 staged
// transpose (coalesced float4 + LDS [i][PSTR] bf16). LDS 35840 B, 2
// blocks/CU. Qt scaled by log2(e).
// ---------------------------------------------------------------------------
#define PSTR 280  // padded row stride (elements); 560 B rows
__global__ __launch_bounds__(512) void qkprep(
    const float* __restrict__ pre, const float* __restrict__ post,
    const unsigned short* __restrict__ WqBf, const float* __restrict__ bq,
    const unsigned short* __restrict__ WkBf, const float* __restrict__ bk,
    const unsigned short* __restrict__ WvBf, const float* __restrict__ bv,
    unsigned short* __restrict__ Qt, unsigned short* __restrict__ Kt,
    unsigned short* __restrict__ VBf)
{
  __shared__ __align__(16) unsigned short smem[2 * 32 * PSTR];  // 35840 B
  unsigned short* sPre  = smem;               // [32 i][PSTR]
  unsigned short* sPost = smem + 32 * PSTR;   // [32 i][PSTR]
  unsigned short* sV    = smem;               // aliased after barrier (20 KB)

  const int tid = threadIdx.x;
  const int lane = tid & 63, w = tid >> 6;    // w in 0..7
  const int quad = lane >> 4, n16 = lane & 15;
  const int b = blockIdx.x >> 7;
  const int i0 = (blockIdx.x & 127) << 5;
  const int isub = w & 1, role = w >> 1;      // role 0..3
  const int i = i0 + isub * 16 + n16;

  // ---- stage: pre/post [256 c][32 i] fp32 -> LDS bf16 [i][c] transposed ----
  // 2048 float4 per tensor; 512 threads x 4 iters.
#pragma unroll
  for (int it = 0; it < 4; it++) {
    const int idx = it * 512 + tid;
    const int c = idx >> 3, ioff = (idx & 7) << 2;
    const size_t goff = ((size_t)b * Cn + c) * Nn + i0 + ioff;
    float4 vp = *(const float4*)(pre + goff);
    float4 vq = *(const float4*)(post + goff);
    sPre[(ioff + 0) * PSTR + c] = f2bf(vp.x);
    sPre[(ioff + 1) * PSTR + c] = f2bf(vp.y);
    sPre[(ioff + 2) * PSTR + c] = f2bf(vp.z);
    sPre[(ioff + 3) * PSTR + c] = f2bf(vp.w);
    sPost[(ioff + 0) * PSTR + c] = f2bf(vq.x);
    sPost[(ioff + 1) * PSTR + c] = f2bf(vq.y);
    sPost[(ioff + 2) * PSTR + c] = f2bf(vq.z);
    sPost[(ioff + 3) * PSTR + c] = f2bf(vq.w);
  }
  __syncthreads();

  const f32x4 zz = {0.f, 0.f, 0.f, 0.f};
  f32x4 aqk = zz;
  f32x4 accv[4];
#pragma unroll
  for (int ct = 0; ct < 4; ct++) accv[ct] = zz;

  const int irow = (isub * 16 + n16) * PSTR;

#pragma unroll
  for (int kc = 0; kc < 8; kc++) {
    const int co = kc * 32 + quad * 8;
    bf16x8 bq8 = ldfrag(sPre + irow + co);    // pre[co..co+7][i] (K and V)
    if (role < 2) {
      bf16x8 bp = ldfrag(sPost + irow + co);  // post[co..co+7][i]
      bf16x8 awq = ldfrag(WqBf + (size_t)(role * 16 + n16) * Cn + co);
      aqk = __builtin_amdgcn_mfma_f32_16x16x32_bf16(awq, bp, aqk, 0, 0, 0);
    } else {
      bf16x8 awk = ldfrag(WkBf + (size_t)((role - 2) * 16 + n16) * Cn + co);
      aqk = __builtin_amdgcn_mfma_f32_16x16x32_bf16(awk, bq8, aqk, 0, 0, 0);
    }
#pragma unroll
    for (int ct = 0; ct < 4; ct++) {
      bf16x8 aw = ldfrag(WvBf + (size_t)(role * 64 + ct * 16 + n16) * Cn + co);
      accv[ct] = __builtin_amdgcn_mfma_f32_16x16x32_bf16(aw, bq8, accv[ct], 0, 0, 0);
    }
  }

  // Q/K epilogue: role<2 writes Q d-half `role`; role>=2 writes K d-half.
  const float LOG2E = 1.44269504f;
  if (role < 2) {
    union { unsigned short s[4]; uint2 u; } oq;
#pragma unroll
    for (int r = 0; r < 4; r++) {
      const int d = role * 16 + quad * 4 + r;
      oq.s[r] = f2bf((aqk[r] + bq[d]) * LOG2E);
    }
    *(uint2*)(Qt + ((size_t)b * Nn + i) * Dn + role * 16 + quad * 4) = oq.u;
  } else {
    union { unsigned short s[4]; uint2 u; } ok;
#pragma unroll
    for (int r = 0; r < 4; r++) {
      const int d = (role - 2) * 16 + quad * 4 + r;
      ok.s[r] = f2bf(aqk[r] + bk[d]);
    }
    *(uint2*)(Kt + ((size_t)b * Nn + i) * Dn + (role - 2) * 16 + quad * 4) = ok.u;
  }

  // V epilogue: reuse smem as sV after all fragment reads done
  __syncthreads();
#pragma unroll
  for (int ct = 0; ct < 4; ct++) {
#pragma unroll
    for (int r = 0; r < 4; r++) {
      const int c = role * 64 + ct * 16 + quad * 4 + r;
      sV[c * 40 + isub * 16 + n16] = f2bf(accv[ct][r] + bv[c]);
    }
  }
  __syncthreads();
#pragma unroll
  for (int k = 0; k < 2; k++) {
    const int slot = tid + k * 512;          // 1024 = 256 c x 4 n-octets
    const int c = slot >> 2, seg = slot & 3;
    *(uint4*)(VBf + ((size_t)b * Cn + c) * Nn + i0 + seg * 8) =
        *(const uint4*)(sV + c * 40 + seg * 8);
  }
}

// ---------------------------------------------------------------------------
// Kernel 2: flash attention v13 (unchanged from R17 best, 66 µs): v9 +
// XCD-aware bijective swizzle (FETCH 37.4 -> 5.7 MB) + setprio around PV.
// ---------------------------------------------------------------------------
__global__ __launch_bounds__(256, 4) void flash_attn(
    const unsigned short* __restrict__ Qt, const unsigned short* __restrict__ Kt,
    const unsigned short* __restrict__ VBf,
    unsigned short* __restrict__ Opart, float* __restrict__ Lpart)
{
  __shared__ __align__(16) unsigned short sX[256 * 64];  // 32 KB
  __shared__ __align__(16) unsigned short Pl[64 * 64];   // 8 KB (swizzled)

  const int tid = threadIdx.x;
  const int lane = tid & 63, w = tid >> 6;
  const int quad = lane >> 4, n16 = lane & 15;
  // XCD-aware decode: pair (bid&7) -> xcd owns (b, js-half); bijective.
  const int bid = blockIdx.x;
  const int pair = bid & 7, sub = bid >> 3;      // sub in 0..127
  const int b  = pair >> 1;
  const int js = ((pair & 1) << 1) | (sub >> 6);
  const int it = sub & 63;
  const int i0 = it * 64;
  const int jbase = js * 1024;

  // Q B-frag for wave's own 16-i subtile (S^T: B n=i, k=d)
  const bf16x8 qf = ldfrag(Qt + ((size_t)b * Nn + i0 + w * 16 + n16) * Dn + quad * 8);

  const f32x4 zz = {0.f, 0.f, 0.f, 0.f};
  f32x4 acc[4][4];                       // [i-sub][c-tile within wave's 64 c]
#pragma unroll
  for (int sub2 = 0; sub2 < 4; sub2++)
#pragma unroll
    for (int ct = 0; ct < 4; ct++) acc[sub2][ct] = zz;
  float lrow = 0.f;                      // softmax denom, col i = n16 (dup x4)

  const size_t laneoff = (size_t)(lane >> 3) * Nn + (size_t)(((lane & 7) ^ (lane >> 3)) << 3);
  const unsigned short* preB = VBf + (size_t)b * Cn * Nn + laneoff;
  const int xsw = n16 & 7;
  const int xoff0 = (quad ^ xsw) << 3;
  const int xoff1 = ((4 + quad) ^ xsw) << 3;
  const int psw = (n16 & 7) << 3;        // Pl XOR swizzle (16B units per 8 rows)

  for (int t = 0; t < 16; ++t) {
    const int j0 = jbase + t * 64;
    __syncthreads();                     // sX(t-1)/Pl(t-1) fully consumed
    // async stage V tile 256c x 64j (XOR col swizzle), 8 x 16B per lane
#pragma unroll
    for (int k = 0; k < 8; k++) {
      const int rb = (k * 4 + w) * 8;
      async16(sX + rb * 64 + (lane << 3), preB + (size_t)rb * Nn + j0);
    }
    // S^T = K Q^T for wave's 16 i; K b128 direct from L2-resident Kt
    {
      f32x4 sc[4];
#pragma unroll
      for (int jt = 0; jt < 4; jt++) {
        bf16x8 akf = ldfrag(Kt + ((size_t)b * Nn + j0 + jt * 16 + n16) * Dn + quad * 8);
        sc[jt] = __builtin_amdgcn_mfma_f32_16x16x32_bf16(akf, qf, zz, 0, 0, 0);
      }
      float ps = 0.f;
#pragma unroll
      for (int jt = 0; jt < 4; jt++) {
        float p0 = exp2f(fminf(sc[jt][0], 101.f));
        float p1 = exp2f(fminf(sc[jt][1], 101.f));
        float p2 = exp2f(fminf(sc[jt][2], 101.f));
        float p3 = exp2f(fminf(sc[jt][3], 101.f));
        ps += (p0 + p1) + (p2 + p3);
        union { unsigned int u2[2]; uint2 u; } pk;
        pk.u2[0] = pk2(p0, p1);
        pk.u2[1] = pk2(p2, p3);
        // Pl[i][j], i = w*16+n16, j = jt*16+quad*4..+3 (XOR-swizzled cols)
        *(uint2*)&Pl[(size_t)(w * 16 + n16) * 64 + ((jt * 16 + quad * 4) ^ psw)] = pk.u;
      }
      ps += __shfl_xor(ps, 16);
      ps += __shfl_xor(ps, 32);
      lrow += ps;
    }
    __syncthreads();                     // DMA drained + Pl visible

    // PV(t): U[c][i] += V[c][j] P^T[j][i], 16x16x32 (k = 32 j)
    __builtin_amdgcn_s_setprio(1);
#pragma unroll
    for (int kc = 0; kc < 2; kc++) {
      const int xo = kc ? xoff1 : xoff0;
      bf16x8 pB[4];
#pragma unroll
      for (int sub2 = 0; sub2 < 4; sub2++)
        pB[sub2] = ldfrag(&Pl[(size_t)(sub2 * 16 + n16) * 64 + ((kc * 32 + quad * 8) ^ psw)]);
#pragma unroll
      for (int ct = 0; ct < 4; ct++) {
        const int crow = w * 64 + ct * 16 + n16;
        bf16x8 av = ldfrag(&sX[crow * 64 + xo]);
        acc[0][ct] = __builtin_amdgcn_mfma_f32_16x16x32_bf16(av, pB[0], acc[0][ct], 0, 0, 0);
        acc[1][ct] = __builtin_amdgcn_mfma_f32_16x16x32_bf16(av, pB[1], acc[1][ct], 0, 0, 0);
        acc[2][ct] = __builtin_amdgcn_mfma_f32_16x16x32_bf16(av, pB[2], acc[2][ct], 0, 0, 0);
        acc[3][ct] = __builtin_amdgcn_mfma_f32_16x16x32_bf16(av, pB[3], acc[3][ct], 0, 0, 0);
      }
    }
    __builtin_amdgcn_s_setprio(0);
  }

  // partial store: O bf16 [js*4+b][i][c], l fp32 [js*4+b][i]
  const size_t pbase = (size_t)(js * 4 + b) * Nn;
  if (quad == 0) Lpart[pbase + i0 + w * 16 + n16] = lrow;
#pragma unroll
  for (int sub2 = 0; sub2 < 4; sub2++) {
    const int i = i0 + sub2 * 16 + n16;
#pragma unroll
    for (int ct = 0; ct < 4; ct++) {
      union { unsigned int u2[2]; uint2 u; } pk;
      pk.u2[0] = pk2(acc[sub2][ct][0], acc[sub2][ct][1]);
      pk.u2[1] = pk2(acc[sub2][ct][2], acc[sub2][ct][3]);
      *(uint2*)(Opart + (pbase + i) * 256 + w * 64 + ct * 16 + quad * 4) = pk.u;
    }
  }
}

// ---------------------------------------------------------------------------
// Kernel 3: combine v2 — pure streaming merge (unchanged, R17 best config).
// ---------------------------------------------------------------------------
__global__ __launch_bounds__(256) void combine(
    const unsigned short* __restrict__ Opart, const float* __restrict__ Lpart,
    const float* __restrict__ post, const float* __restrict__ gamma,
    float* __restrict__ out)
{
  __shared__ float sT[64 * 65];   // [c][i], stride 65
  __shared__ float sL[64];

  const int tid = threadIdx.x;
  const int b = blockIdx.x >> 8;
  const int rest = blockIdx.x & 255;
  const int i0 = (rest >> 2) * 64;
  const int c0 = (rest & 3) * 64;

  if (tid < 64) {
    float l = 0.f;
#pragma unroll
    for (int js = 0; js < 4; js++) l += Lpart[(size_t)(js * 4 + b) * Nn + i0 + tid];
    sL[tid] = 1.f / l;
  }
  __syncthreads();

  // accumulate 4 partials, normalize, write transposed into sT
#pragma unroll
  for (int pass = 0; pass < 2; pass++) {
    const int il = (tid >> 3) + pass * 32;   // 0..63
    const int c8 = (tid & 7) << 3;           // 0..56
    float a[8] = {0.f, 0.f, 0.f, 0.f, 0.f, 0.f, 0.f, 0.f};
#pragma unroll
    for (int js = 0; js < 4; js++) {
      uint4 uu = *(const uint4*)(Opart + ((size_t)(js * 4 + b) * Nn + i0 + il) * 256 + c0 + c8);
      const unsigned short* us = (const unsigned short*)&uu;
#pragma unroll
      for (int e = 0; e < 8; e++) a[e] += bf2f(us[e]);
    }
    const float inv = sL[il];
#pragma unroll
    for (int e = 0; e < 8; e++) sT[(c8 + e) * 65 + il] = a[e] * inv;
  }
  __syncthreads();

  const float g = gamma[0];
#pragma unroll
  for (int itr = 0; itr < 4; itr++) {
    const int slot = tid + itr * 256;        // 1024 = 64 c x 16 i-quads
    const int cr = slot >> 4, i4 = (slot & 15) << 2;
    const size_t addr = ((size_t)b * Cn + c0 + cr) * Nn + i0 + i4;
    float4 pp = *(const float4*)(post + addr);
    float4 ov;
    ov.x = g * sT[cr * 65 + i4 + 0] + pp.x;
    ov.y = g * sT[cr * 65 + i4 + 1] + pp.y;
    ov.z = g * sT[cr * 65 + i4 + 2] + pp.z;
    ov.w = g * sT[cr * 65 + i4 + 3] + pp.w;
    *(float4*)(out + addr) = ov;
  }
}

extern "C" void kernel_launch(void* const* d_in, const int* in_sizes, int n_in,
                              void* d_out, int out_size, void* d_ws, size_t ws_size,
                              hipStream_t stream) {
  const float* pre   = (const float*)d_in[0];
  const float* post  = (const float*)d_in[1];
  const float* Wq    = (const float*)d_in[2];
  const float* bq    = (const float*)d_in[3];
  const float* Wk    = (const float*)d_in[4];
  const float* bk    = (const float*)d_in[5];
  const float* Wv    = (const float*)d_in[6];
  const float* bv    = (const float*)d_in[7];
  const float* gamma = (const float*)d_in[8];
  float* out = (float*)d_out;

  unsigned short* ws = (unsigned short*)d_ws;
  unsigned short* Qt    = ws;                                   // 512K sh
  unsigned short* Kt    = Qt + (size_t)Bn * Nn * Dn;            // 512K sh
  unsigned short* VBf   = Kt + (size_t)Bn * Nn * Dn;            // 4M sh
  unsigned short* WqBf  = VBf + (size_t)Bn * Cn * Nn;           // 8K sh
  unsigned short* WkBf  = WqBf + Dn * Cn;                       // 8K sh
  unsigned short* WvBf  = WkBf + Dn * Cn;                       // 64K sh
  float* Lpart = (float*)(WvBf + Cn * Cn);                      // 64K fl
  unsigned short* Opart = (unsigned short*)(Lpart + 4 * Bn * Nn);  // 16.7M sh

  wconv<<<40, 256, 0, stream>>>(Wq, Wk, Wv, WqBf, WkBf, WvBf);
  qkprep<<<512, 512, 0, stream>>>(pre, post, WqBf, bq, WkBf, bk, WvBf, bv,
                                  Qt, Kt, VBf);
  flash_attn<<<1024, 256, 0, stream>>>(Qt, Kt, VBf, Opart, Lpart);
  combine<<<1024, 256, 0, stream>>>(Opart, Lpart, post, gamma, out);
}